// Round 6
// baseline (817.636 us; speedup 1.0000x reference)
//
#include <hip/hip_runtime.h>

#define N_NODES 50000
#define N_EDGES 800000
#define DIM 128
#define OUTD 47
#define NB_SCAN ((N_NODES + 255) / 256) // 196 (row_ptr scan blocks)
#define NBK 196                         // dst buckets of 256 nodes (49999>>8 = 195)
#define EPB 4096                        // edges per k_bin block
#define NBIN ((N_EDGES + EPB - 1) / EPB) // 196

typedef __attribute__((ext_vector_type(8))) short v8s;
typedef __attribute__((ext_vector_type(4))) float v4f;
typedef __attribute__((ext_vector_type(2))) float v2f;

static __device__ __forceinline__ unsigned short f2bf(float f) {
    union { float f; unsigned int u; } v; v.f = f;
    unsigned int x = v.u;
    return (unsigned short)((x + 0x7fffu + ((x >> 16) & 1u)) >> 16); // RNE
}
static __device__ __forceinline__ float lo_bf(unsigned int u) {
    union { unsigned int i; float f; } v; v.i = u << 16; return v.f;
}
static __device__ __forceinline__ float hi_bf(unsigned int u) {
    union { unsigned int i; float f; } v; v.i = u & 0xffff0000u; return v.f;
}

// ---------------- CSR build ----------------
__global__ void k_count(const int* __restrict__ dst, int* __restrict__ deg,
                        int* __restrict__ bhist) {
    int e = blockIdx.x * 256 + threadIdx.x;
    if (e < N_EDGES) {
        int d = dst[e];
        atomicAdd(&deg[d], 1);
        atomicAdd(&bhist[d >> 8], 1);
    }
}

__global__ __launch_bounds__(256) void k_bsum(const int* __restrict__ deg,
                                              int* __restrict__ bsum) {
    __shared__ int s[256];
    int i = blockIdx.x * 256 + threadIdx.x;
    int v = (i < N_NODES) ? deg[i] : 0;
    s[threadIdx.x] = v;
    __syncthreads();
    for (int off = 128; off > 0; off >>= 1) {
        if (threadIdx.x < off) s[threadIdx.x] += s[threadIdx.x + off];
        __syncthreads();
    }
    if (threadIdx.x == 0) bsum[blockIdx.x] = s[0];
}

__global__ __launch_bounds__(256) void k_scanb(const int* __restrict__ bsum,
                                               int* __restrict__ boff,
                                               int* __restrict__ row_ptr) {
    __shared__ int s[256];
    int t = threadIdx.x;
    int v = (t < NB_SCAN) ? bsum[t] : 0;
    s[t] = v;
    __syncthreads();
    for (int off = 1; off < 256; off <<= 1) {
        int u = (t >= off) ? s[t - off] : 0;
        __syncthreads();
        s[t] += u;
        __syncthreads();
    }
    if (t < NB_SCAN) boff[t] = s[t] - v;
    if (t == 255) row_ptr[N_NODES] = s[255];
}

__global__ __launch_bounds__(256) void k_scatter(const int* __restrict__ deg,
                                                 const int* __restrict__ boff,
                                                 int* __restrict__ row_ptr) {
    __shared__ int s[256];
    int t = threadIdx.x;
    int i = blockIdx.x * 256 + t;
    int v = (i < N_NODES) ? deg[i] : 0;
    s[t] = v;
    __syncthreads();
    for (int off = 1; off < 256; off <<= 1) {
        int u = (t >= off) ? s[t - off] : 0;
        __syncthreads();
        s[t] += u;
        __syncthreads();
    }
    if (i < N_NODES) row_ptr[i] = s[t] - v + boff[blockIdx.x];
}

// scan bucket hist -> bucket bases (boffB) + working cursors (gcur)
__global__ __launch_bounds__(256) void k_scanbkt(const int* __restrict__ bhist,
                                                 int* __restrict__ boffB,
                                                 int* __restrict__ gcur) {
    __shared__ int s[256];
    int t = threadIdx.x;
    int v = (t < NBK) ? bhist[t] : 0;
    s[t] = v;
    __syncthreads();
    for (int off = 1; off < 256; off <<= 1) {
        int u = (t >= off) ? s[t - off] : 0;
        __syncthreads();
        s[t] += u;
        __syncthreads();
    }
    if (t < NBK) { int ex = s[t] - v; boffB[t] = ex; gcur[t] = ex; }
}

// bin edges by dst>>8 into bucket-contiguous packed runs (src<<8 | dst&255)
__global__ __launch_bounds__(256) void k_bin(const int* __restrict__ src,
                                             const int* __restrict__ dst,
                                             int* __restrict__ gcur,
                                             unsigned int* __restrict__ packed) {
    __shared__ int hist[NBK], gbase[NBK], cnt[NBK];
    int t = threadIdx.x;
    for (int i = t; i < NBK; i += 256) { hist[i] = 0; cnt[i] = 0; }
    __syncthreads();
    const int e0 = blockIdx.x * EPB;
    const int ecnt = min(EPB, N_EDGES - e0);
    for (int r = t; r < ecnt; r += 256)
        atomicAdd(&hist[dst[e0 + r] >> 8], 1);
    __syncthreads();
    if (t < NBK) gbase[t] = atomicAdd(&gcur[t], hist[t]);
    __syncthreads();
    for (int r = t; r < ecnt; r += 256) {
        int s = src[e0 + r], d = dst[e0 + r];
        int b = d >> 8;
        int loc = atomicAdd(&cnt[b], 1);
        packed[gbase[b] + loc] = ((unsigned int)s << 8) | (unsigned int)(d & 255);
    }
}

// per-bucket placement: one block owns one bucket's 256 dst nodes + its packed run
__global__ __launch_bounds__(256) void k_place(const unsigned int* __restrict__ packed,
                                               const int* __restrict__ boffB,
                                               const int* __restrict__ bhist,
                                               const int* __restrict__ row_ptr,
                                               int* __restrict__ src_sorted) {
    __shared__ int cur[256];
    const int b = blockIdx.x, t = threadIdx.x;
    int node = b * 256 + t;
    cur[t] = (node < N_NODES) ? row_ptr[node] : 0;
    __syncthreads();
    const int base = boffB[b], cb = bhist[b];
    for (int i = t; i < cb; i += 256) {
        unsigned int pkt = packed[base + i];
        int pos = atomicAdd(&cur[pkt & 255u], 1);
        src_sorted[pos] = (int)(pkt >> 8);
    }
}

// ---------------- conversions ----------------
__global__ __launch_bounds__(256) void k_xcvt(const float* __restrict__ x,
                                              unsigned short* __restrict__ xb) {
    int i = blockIdx.x * 256 + threadIdx.x; // one float4 per thread
    float4 v = ((const float4*)x)[i];
    ushort4 o;
    o.x = f2bf(v.x); o.y = f2bf(v.y); o.z = f2bf(v.z); o.w = f2bf(v.w);
    ((ushort4*)xb)[i] = o;
}

// bf16 -> fp8 e4m3 (OCP), 8 elems per thread
__global__ __launch_bounds__(256) void k_cvt8(const unsigned int* __restrict__ hb,
                                              unsigned int* __restrict__ h8) {
    int i = blockIdx.x * 256 + threadIdx.x;
    uint4 u = ((const uint4*)hb)[i];
    float f0 = lo_bf(u.x), f1 = hi_bf(u.x), f2 = lo_bf(u.y), f3 = hi_bf(u.y);
    float f4 = lo_bf(u.z), f5 = hi_bf(u.z), f6 = lo_bf(u.w), f7 = hi_bf(u.w);
    unsigned int a = __builtin_amdgcn_cvt_pk_fp8_f32(f0, f1, 0, false);
    a = __builtin_amdgcn_cvt_pk_fp8_f32(f2, f3, a, true);
    unsigned int b = __builtin_amdgcn_cvt_pk_fp8_f32(f4, f5, 0, false);
    b = __builtin_amdgcn_cvt_pk_fp8_f32(f6, f7, b, true);
    uint2 o; o.x = a; o.y = b;
    ((uint2*)h8)[i] = o;
}

__global__ void k_wcvt(const float* __restrict__ wself, const float* __restrict__ wneigh,
                       unsigned short* __restrict__ out, int J) {
    int idx = blockIdx.x * 256 + threadIdx.x;
    int j = idx >> 8, k = idx & 255;
    float v = 0.f;
    if (j < J) v = (k < DIM) ? wself[j * DIM + k] : wneigh[j * DIM + (k - DIM)];
    out[idx] = f2bf(v);
}

// ---------------- mean aggregation: fp8 in / bf16 out, fp32 accumulate ----------------
// one wave per node; lane l owns features 2l, 2l+1 (ushort = 2 fp8 per row)
__global__ __launch_bounds__(256) void k_agg8(const unsigned char* __restrict__ h8,
                                              const int* __restrict__ row_ptr,
                                              const int* __restrict__ srcs,
                                              unsigned short* __restrict__ meanb) {
    const int w = threadIdx.x >> 6;
    const int l = threadIdx.x & 63;
    const int n = blockIdx.x * 4 + w;
    const int start = row_ptr[n], end = row_ptr[n + 1]; // wave-uniform
    const unsigned short* __restrict__ hp = (const unsigned short*)h8;
    float ax = 0.f, ay = 0.f;
    int e = start;
    for (; e + 4 <= end; e += 4) {
        int s0 = __builtin_amdgcn_readfirstlane(srcs[e]);
        int s1 = __builtin_amdgcn_readfirstlane(srcs[e + 1]);
        int s2 = __builtin_amdgcn_readfirstlane(srcs[e + 2]);
        int s3 = __builtin_amdgcn_readfirstlane(srcs[e + 3]);
        unsigned int u0 = hp[(size_t)s0 * 64 + l];
        unsigned int u1 = hp[(size_t)s1 * 64 + l];
        unsigned int u2 = hp[(size_t)s2 * 64 + l];
        unsigned int u3 = hp[(size_t)s3 * 64 + l];
        v2f f0 = __builtin_amdgcn_cvt_pk_f32_fp8(u0, false);
        v2f f1 = __builtin_amdgcn_cvt_pk_f32_fp8(u1, false);
        v2f f2 = __builtin_amdgcn_cvt_pk_f32_fp8(u2, false);
        v2f f3 = __builtin_amdgcn_cvt_pk_f32_fp8(u3, false);
        ax += (f0[0] + f1[0]) + (f2[0] + f3[0]);
        ay += (f0[1] + f1[1]) + (f2[1] + f3[1]);
    }
    for (; e < end; ++e) {
        int s0 = __builtin_amdgcn_readfirstlane(srcs[e]);
        v2f f0 = __builtin_amdgcn_cvt_pk_f32_fp8((unsigned int)hp[(size_t)s0 * 64 + l], false);
        ax += f0[0]; ay += f0[1];
    }
    int d = end - start;
    float inv = (d > 0) ? 1.f / (float)d : 0.f;
    ushort2 r; r.x = f2bf(ax * inv); r.y = f2bf(ay * inv);
    ((ushort2*)meanb)[(size_t)n * 64 + l] = r;
}

// ---------------- MFMA GEMM (unchanged from round 5) ----------------
template <int NTILES, bool RELU, bool OUTBF>
__global__ __launch_bounds__(256) void k_gemm_mfma(const unsigned short* __restrict__ Ab,
                                                   const unsigned short* __restrict__ Mb,
                                                   const unsigned short* __restrict__ Wb,
                                                   const float* __restrict__ bias,
                                                   void* __restrict__ out, int outdim) {
    const int lane = threadIdx.x & 63;
    const int wv = threadIdx.x >> 6;
    const int m0 = (blockIdx.x * 4 + wv) * 16;
    const int m = lane & 15, qd = lane >> 4;
    int node = m0 + m; if (node >= N_NODES) node = N_NODES - 1;
    const unsigned short* __restrict__ arow = Ab + (size_t)node * DIM;
    const unsigned short* __restrict__ mrow = Mb + (size_t)node * DIM;

    v4f acc[NTILES] = {};
    #pragma unroll
    for (int c = 0; c < 8; ++c) {
        const unsigned short* __restrict__ srow = (c < 4) ? arow : mrow;
        v8s af = *(const v8s*)(srow + (c & 3) * 32 + qd * 8);
        const int kglob = c * 32 + qd * 8;
        #pragma unroll
        for (int t = 0; t < NTILES; ++t) {
            v8s wf = *(const v8s*)(Wb + (size_t)(t * 16 + m) * 256 + kglob);
            acc[t] = __builtin_amdgcn_mfma_f32_16x16x32_bf16(af, wf, acc[t], 0, 0, 0);
        }
    }
    #pragma unroll
    for (int t = 0; t < NTILES; ++t) {
        int col = t * 16 + m;
        bool colok = (col < outdim);
        float bv = colok ? bias[col] : 0.f;
        #pragma unroll
        for (int r = 0; r < 4; ++r) {
            int nrow = m0 + qd * 4 + r;
            if (colok && nrow < N_NODES) {
                float v = acc[t][r] + bv;
                if (RELU) v = fmaxf(v, 0.f);
                if (OUTBF) ((unsigned short*)out)[(size_t)nrow * outdim + col] = f2bf(v);
                else       ((float*)out)[(size_t)nrow * outdim + col] = v;
            }
        }
    }
}

extern "C" void kernel_launch(void* const* d_in, const int* in_sizes, int n_in,
                              void* d_out, int out_size, void* d_ws, size_t ws_size,
                              hipStream_t stream) {
    const float* x   = (const float*)d_in[0];
    const int*   src = (const int*)d_in[1];
    const int*   dst = (const int*)d_in[2];
    const float* ws1 = (const float*)d_in[3];
    const float* wn1 = (const float*)d_in[4];
    const float* b1  = (const float*)d_in[5];
    const float* ws2 = (const float*)d_in[6];
    const float* wn2 = (const float*)d_in[7];
    const float* b2  = (const float*)d_in[8];
    const float* ws3 = (const float*)d_in[9];
    const float* wn3 = (const float*)d_in[10];
    const float* b3  = (const float*)d_in[11];

    char* p = (char*)d_ws;
    auto alloc = [&](size_t bytes) { char* r = p; p += (bytes + 255) & ~(size_t)255; return r; };
    int*   deg     = (int*)alloc((size_t)N_NODES * 4);
    int*   bhist   = (int*)alloc((size_t)NBK * 4);
    int*   row_ptr = (int*)alloc((size_t)(N_NODES + 1) * 4);
    int*   srcs    = (int*)alloc((size_t)N_EDGES * 4);
    unsigned int* packed = (unsigned int*)alloc((size_t)N_EDGES * 4);
    int*   bsum    = (int*)alloc((size_t)NB_SCAN * 4);
    int*   boff    = (int*)alloc((size_t)NB_SCAN * 4);
    int*   boffB   = (int*)alloc((size_t)NBK * 4);
    int*   gcur    = (int*)alloc((size_t)NBK * 4);
    unsigned short* xb    = (unsigned short*)alloc((size_t)N_NODES * DIM * 2);
    unsigned short* meanb = (unsigned short*)alloc((size_t)N_NODES * DIM * 2);
    unsigned short* h1b   = (unsigned short*)alloc((size_t)N_NODES * DIM * 2);
    unsigned short* h2b   = (unsigned short*)alloc((size_t)N_NODES * DIM * 2);
    unsigned char*  h8    = (unsigned char*)alloc((size_t)N_NODES * DIM);
    unsigned short* wb1 = (unsigned short*)alloc((size_t)DIM * 256 * 2);
    unsigned short* wb2 = (unsigned short*)alloc((size_t)DIM * 256 * 2);
    unsigned short* wb3 = (unsigned short*)alloc((size_t)48 * 256 * 2);

    // conversions
    k_xcvt<<<N_NODES * DIM / 4 / 256, 256, 0, stream>>>(x, xb);
    k_cvt8<<<N_NODES * DIM / 8 / 256, 256, 0, stream>>>((const unsigned int*)xb, (unsigned int*)h8);
    k_wcvt<<<DIM, 256, 0, stream>>>(ws1, wn1, wb1, DIM);
    k_wcvt<<<DIM, 256, 0, stream>>>(ws2, wn2, wb2, DIM);
    k_wcvt<<<48,  256, 0, stream>>>(ws3, wn3, wb3, OUTD);

    // CSR build, binned (ws re-poisoned every call -> rebuild every call)
    hipMemsetAsync(deg, 0, (size_t)N_NODES * 4, stream);
    hipMemsetAsync(bhist, 0, (size_t)NBK * 4, stream);
    k_count<<<(N_EDGES + 255) / 256, 256, 0, stream>>>(dst, deg, bhist);
    k_bsum<<<NB_SCAN, 256, 0, stream>>>(deg, bsum);
    k_scanb<<<1, 256, 0, stream>>>(bsum, boff, row_ptr);
    k_scatter<<<NB_SCAN, 256, 0, stream>>>(deg, boff, row_ptr);
    k_scanbkt<<<1, 256, 0, stream>>>(bhist, boffB, gcur);
    k_bin<<<NBIN, 256, 0, stream>>>(src, dst, gcur, packed);
    k_place<<<NBK, 256, 0, stream>>>(packed, boffB, bhist, row_ptr, srcs);

    const int GB = (N_NODES + 63) / 64;

    // layer 1
    k_agg8<<<N_NODES / 4, 256, 0, stream>>>(h8, row_ptr, srcs, meanb);
    k_gemm_mfma<8, true, true><<<GB, 256, 0, stream>>>(xb, meanb, wb1, b1, h1b, DIM);
    k_cvt8<<<N_NODES * DIM / 8 / 256, 256, 0, stream>>>((const unsigned int*)h1b, (unsigned int*)h8);
    // layer 2
    k_agg8<<<N_NODES / 4, 256, 0, stream>>>(h8, row_ptr, srcs, meanb);
    k_gemm_mfma<8, true, true><<<GB, 256, 0, stream>>>(h1b, meanb, wb2, b2, h2b, DIM);
    k_cvt8<<<N_NODES * DIM / 8 / 256, 256, 0, stream>>>((const unsigned int*)h2b, (unsigned int*)h8);
    // layer 3
    k_agg8<<<N_NODES / 4, 256, 0, stream>>>(h8, row_ptr, srcs, meanb);
    k_gemm_mfma<3, false, false><<<GB, 256, 0, stream>>>(h2b, meanb, wb3, b3, d_out, OUTD);
}

// Round 7
// 369.435 us; speedup vs baseline: 2.2132x; 2.2132x over previous
//
#include <hip/hip_runtime.h>

#define N_NODES 50000
#define N_EDGES 800000
#define DIM 128
#define OUTD 47
#define NB_SCAN ((N_NODES + 255) / 256) // 196 (row_ptr scan blocks == dst buckets)
#define NBK 196                         // dst buckets of 256 nodes
#define EPB 4096                        // edges per k_bin block
#define NBIN ((N_EDGES + EPB - 1) / EPB) // 196

typedef __attribute__((ext_vector_type(8))) short v8s;
typedef __attribute__((ext_vector_type(4))) float v4f;
typedef __attribute__((ext_vector_type(2))) float v2f;

static __device__ __forceinline__ unsigned short f2bf(float f) {
    union { float f; unsigned int u; } v; v.f = f;
    unsigned int x = v.u;
    return (unsigned short)((x + 0x7fffu + ((x >> 16) & 1u)) >> 16); // RNE
}
static __device__ __forceinline__ float lo_bf(unsigned int u) {
    union { unsigned int i; float f; } v; v.i = u << 16; return v.f;
}
static __device__ __forceinline__ float hi_bf(unsigned int u) {
    union { unsigned int i; float f; } v; v.i = u & 0xffff0000u; return v.f;
}
static __device__ __forceinline__ unsigned char f2fp8(float f) {
    unsigned int pk = __builtin_amdgcn_cvt_pk_fp8_f32(f, f, 0, false);
    return (unsigned char)(pk & 0xffu);
}

// ---------------- CSR build ----------------
// deg-only atomics: 50k distinct addresses, no bucket histogram here
// (bucket hist == k_bsum's block sums; the round-6 bhist atomics cost 473 us)
__global__ void k_count(const int* __restrict__ dst, int* __restrict__ deg) {
    int e = blockIdx.x * 256 + threadIdx.x;
    if (e < N_EDGES) atomicAdd(&deg[dst[e]], 1);
}

__global__ __launch_bounds__(256) void k_bsum(const int* __restrict__ deg,
                                              int* __restrict__ bsum) {
    __shared__ int s[256];
    int i = blockIdx.x * 256 + threadIdx.x;
    int v = (i < N_NODES) ? deg[i] : 0;
    s[threadIdx.x] = v;
    __syncthreads();
    for (int off = 128; off > 0; off >>= 1) {
        if (threadIdx.x < off) s[threadIdx.x] += s[threadIdx.x + off];
        __syncthreads();
    }
    if (threadIdx.x == 0) bsum[blockIdx.x] = s[0];
}

__global__ __launch_bounds__(256) void k_scanb(const int* __restrict__ bsum,
                                               int* __restrict__ boff,
                                               int* __restrict__ row_ptr) {
    __shared__ int s[256];
    int t = threadIdx.x;
    int v = (t < NB_SCAN) ? bsum[t] : 0;
    s[t] = v;
    __syncthreads();
    for (int off = 1; off < 256; off <<= 1) {
        int u = (t >= off) ? s[t - off] : 0;
        __syncthreads();
        s[t] += u;
        __syncthreads();
    }
    if (t < NB_SCAN) boff[t] = s[t] - v;
    if (t == 255) row_ptr[N_NODES] = s[255];
}

__global__ __launch_bounds__(256) void k_scatter(const int* __restrict__ deg,
                                                 const int* __restrict__ boff,
                                                 int* __restrict__ row_ptr) {
    __shared__ int s[256];
    int t = threadIdx.x;
    int i = blockIdx.x * 256 + t;
    int v = (i < N_NODES) ? deg[i] : 0;
    s[t] = v;
    __syncthreads();
    for (int off = 1; off < 256; off <<= 1) {
        int u = (t >= off) ? s[t - off] : 0;
        __syncthreads();
        s[t] += u;
        __syncthreads();
    }
    if (i < N_NODES) row_ptr[i] = s[t] - v + boff[blockIdx.x];
}

// scan bucket sums (== bucket hist) -> bucket bases + working cursors
__global__ __launch_bounds__(256) void k_scanbkt(const int* __restrict__ bsum,
                                                 int* __restrict__ boffB,
                                                 int* __restrict__ gcur) {
    __shared__ int s[256];
    int t = threadIdx.x;
    int v = (t < NBK) ? bsum[t] : 0;
    s[t] = v;
    __syncthreads();
    for (int off = 1; off < 256; off <<= 1) {
        int u = (t >= off) ? s[t - off] : 0;
        __syncthreads();
        s[t] += u;
        __syncthreads();
    }
    if (t < NBK) { int ex = s[t] - v; boffB[t] = ex; gcur[t] = ex; }
}

// bin edges by dst>>8 into bucket-contiguous packed runs (src<<8 | dst&255)
__global__ __launch_bounds__(256) void k_bin(const int* __restrict__ src,
                                             const int* __restrict__ dst,
                                             int* __restrict__ gcur,
                                             unsigned int* __restrict__ packed) {
    __shared__ int hist[NBK], gbase[NBK], cnt[NBK];
    int t = threadIdx.x;
    for (int i = t; i < NBK; i += 256) { hist[i] = 0; cnt[i] = 0; }
    __syncthreads();
    const int e0 = blockIdx.x * EPB;
    const int ecnt = min(EPB, N_EDGES - e0);
    for (int r = t; r < ecnt; r += 256)
        atomicAdd(&hist[dst[e0 + r] >> 8], 1); // LDS atomics, 196-way spread
    __syncthreads();
    if (t < NBK) gbase[t] = atomicAdd(&gcur[t], hist[t]); // 1 global atomic per bucket
    __syncthreads();
    for (int r = t; r < ecnt; r += 256) {
        int s = src[e0 + r], d = dst[e0 + r];
        int b = d >> 8;
        int loc = atomicAdd(&cnt[b], 1);
        packed[gbase[b] + loc] = ((unsigned int)s << 8) | (unsigned int)(d & 255);
    }
}

// per-bucket placement: one block owns one bucket's 256 dst nodes + its packed run
__global__ __launch_bounds__(256) void k_place(const unsigned int* __restrict__ packed,
                                               const int* __restrict__ boffB,
                                               const int* __restrict__ bsum,
                                               const int* __restrict__ row_ptr,
                                               int* __restrict__ src_sorted) {
    __shared__ int cur[256];
    const int b = blockIdx.x, t = threadIdx.x;
    int node = b * 256 + t;
    cur[t] = (node < N_NODES) ? row_ptr[node] : 0;
    __syncthreads();
    const int base = boffB[b], cb = bsum[b];
    for (int i = t; i < cb; i += 256) {
        unsigned int pkt = packed[base + i];
        int pos = atomicAdd(&cur[pkt & 255u], 1);
        src_sorted[pos] = (int)(pkt >> 8); // writes land in this bucket's ~16KB region
    }
}

// ---------------- x -> bf16 + fp8 (fused) ----------------
__global__ __launch_bounds__(256) void k_xcvt(const float* __restrict__ x,
                                              unsigned short* __restrict__ xb,
                                              unsigned int* __restrict__ x8) {
    int i = blockIdx.x * 256 + threadIdx.x; // 8 elems per thread
    float4 v0 = ((const float4*)x)[i * 2];
    float4 v1 = ((const float4*)x)[i * 2 + 1];
    ushort4 o0, o1;
    o0.x = f2bf(v0.x); o0.y = f2bf(v0.y); o0.z = f2bf(v0.z); o0.w = f2bf(v0.w);
    o1.x = f2bf(v1.x); o1.y = f2bf(v1.y); o1.z = f2bf(v1.z); o1.w = f2bf(v1.w);
    ((ushort4*)xb)[i * 2] = o0;
    ((ushort4*)xb)[i * 2 + 1] = o1;
    unsigned int a = __builtin_amdgcn_cvt_pk_fp8_f32(v0.x, v0.y, 0, false);
    a = __builtin_amdgcn_cvt_pk_fp8_f32(v0.z, v0.w, a, true);
    unsigned int b = __builtin_amdgcn_cvt_pk_fp8_f32(v1.x, v1.y, 0, false);
    b = __builtin_amdgcn_cvt_pk_fp8_f32(v1.z, v1.w, b, true);
    uint2 o; o.x = a; o.y = b;
    ((uint2*)x8)[i] = o;
}

__global__ void k_wcvt(const float* __restrict__ wself, const float* __restrict__ wneigh,
                       unsigned short* __restrict__ out, int J) {
    int idx = blockIdx.x * 256 + threadIdx.x;
    int j = idx >> 8, k = idx & 255;
    float v = 0.f;
    if (j < J) v = (k < DIM) ? wself[j * DIM + k] : wneigh[j * DIM + (k - DIM)];
    out[idx] = f2bf(v);
}

// ---------------- mean aggregation: fp8 in / bf16 out, fp32 accumulate ----------------
__global__ __launch_bounds__(256) void k_agg8(const unsigned char* __restrict__ h8,
                                              const int* __restrict__ row_ptr,
                                              const int* __restrict__ srcs,
                                              unsigned short* __restrict__ meanb) {
    const int w = threadIdx.x >> 6;
    const int l = threadIdx.x & 63;
    const int n = blockIdx.x * 4 + w;
    const int start = row_ptr[n], end = row_ptr[n + 1]; // wave-uniform
    const unsigned short* __restrict__ hp = (const unsigned short*)h8;
    float ax = 0.f, ay = 0.f;
    int e = start;
    for (; e + 4 <= end; e += 4) {
        int s0 = __builtin_amdgcn_readfirstlane(srcs[e]);
        int s1 = __builtin_amdgcn_readfirstlane(srcs[e + 1]);
        int s2 = __builtin_amdgcn_readfirstlane(srcs[e + 2]);
        int s3 = __builtin_amdgcn_readfirstlane(srcs[e + 3]);
        unsigned int u0 = hp[(size_t)s0 * 64 + l];
        unsigned int u1 = hp[(size_t)s1 * 64 + l];
        unsigned int u2 = hp[(size_t)s2 * 64 + l];
        unsigned int u3 = hp[(size_t)s3 * 64 + l];
        v2f f0 = __builtin_amdgcn_cvt_pk_f32_fp8(u0, false);
        v2f f1 = __builtin_amdgcn_cvt_pk_f32_fp8(u1, false);
        v2f f2 = __builtin_amdgcn_cvt_pk_f32_fp8(u2, false);
        v2f f3 = __builtin_amdgcn_cvt_pk_f32_fp8(u3, false);
        ax += (f0[0] + f1[0]) + (f2[0] + f3[0]);
        ay += (f0[1] + f1[1]) + (f2[1] + f3[1]);
    }
    for (; e < end; ++e) {
        int s0 = __builtin_amdgcn_readfirstlane(srcs[e]);
        v2f f0 = __builtin_amdgcn_cvt_pk_f32_fp8((unsigned int)hp[(size_t)s0 * 64 + l], false);
        ax += f0[0]; ay += f0[1];
    }
    int d = end - start;
    float inv = (d > 0) ? 1.f / (float)d : 0.f;
    ushort2 r; r.x = f2bf(ax * inv); r.y = f2bf(ay * inv);
    ((ushort2*)meanb)[(size_t)n * 64 + l] = r;
}

// ---------------- MFMA GEMM; epilogue optionally emits bf16 h AND fp8 h ----------------
template <int NTILES, bool RELU, bool OUTBF>
__global__ __launch_bounds__(256) void k_gemm_mfma(const unsigned short* __restrict__ Ab,
                                                   const unsigned short* __restrict__ Mb,
                                                   const unsigned short* __restrict__ Wb,
                                                   const float* __restrict__ bias,
                                                   void* __restrict__ out,
                                                   unsigned char* __restrict__ out8,
                                                   int outdim) {
    const int lane = threadIdx.x & 63;
    const int wv = threadIdx.x >> 6;
    const int m0 = (blockIdx.x * 4 + wv) * 16;
    const int m = lane & 15, qd = lane >> 4;
    int node = m0 + m; if (node >= N_NODES) node = N_NODES - 1;
    const unsigned short* __restrict__ arow = Ab + (size_t)node * DIM;
    const unsigned short* __restrict__ mrow = Mb + (size_t)node * DIM;

    v4f acc[NTILES] = {};
    #pragma unroll
    for (int c = 0; c < 8; ++c) {
        const unsigned short* __restrict__ srow = (c < 4) ? arow : mrow;
        v8s af = *(const v8s*)(srow + (c & 3) * 32 + qd * 8);
        const int kglob = c * 32 + qd * 8;
        #pragma unroll
        for (int t = 0; t < NTILES; ++t) {
            v8s wf = *(const v8s*)(Wb + (size_t)(t * 16 + m) * 256 + kglob);
            acc[t] = __builtin_amdgcn_mfma_f32_16x16x32_bf16(af, wf, acc[t], 0, 0, 0);
        }
    }
    #pragma unroll
    for (int t = 0; t < NTILES; ++t) {
        int col = t * 16 + m;
        bool colok = (col < outdim);
        float bv = colok ? bias[col] : 0.f;
        #pragma unroll
        for (int r = 0; r < 4; ++r) {
            int nrow = m0 + qd * 4 + r;
            if (colok && nrow < N_NODES) {
                float v = acc[t][r] + bv;
                if (RELU) v = fmaxf(v, 0.f);
                size_t idx = (size_t)nrow * outdim + col;
                if (OUTBF) {
                    ((unsigned short*)out)[idx] = f2bf(v);
                    out8[idx] = f2fp8(v);
                } else {
                    ((float*)out)[idx] = v;
                }
            }
        }
    }
}

extern "C" void kernel_launch(void* const* d_in, const int* in_sizes, int n_in,
                              void* d_out, int out_size, void* d_ws, size_t ws_size,
                              hipStream_t stream) {
    const float* x   = (const float*)d_in[0];
    const int*   src = (const int*)d_in[1];
    const int*   dst = (const int*)d_in[2];
    const float* ws1 = (const float*)d_in[3];
    const float* wn1 = (const float*)d_in[4];
    const float* b1  = (const float*)d_in[5];
    const float* ws2 = (const float*)d_in[6];
    const float* wn2 = (const float*)d_in[7];
    const float* b2  = (const float*)d_in[8];
    const float* ws3 = (const float*)d_in[9];
    const float* wn3 = (const float*)d_in[10];
    const float* b3  = (const float*)d_in[11];

    char* p = (char*)d_ws;
    auto alloc = [&](size_t bytes) { char* r = p; p += (bytes + 255) & ~(size_t)255; return r; };
    int*   deg     = (int*)alloc((size_t)N_NODES * 4);
    int*   row_ptr = (int*)alloc((size_t)(N_NODES + 1) * 4);
    int*   srcs    = (int*)alloc((size_t)N_EDGES * 4);
    unsigned int* packed = (unsigned int*)alloc((size_t)N_EDGES * 4);
    int*   bsum    = (int*)alloc((size_t)NB_SCAN * 4);
    int*   boff    = (int*)alloc((size_t)NB_SCAN * 4);
    int*   boffB   = (int*)alloc((size_t)NBK * 4);
    int*   gcur    = (int*)alloc((size_t)NBK * 4);
    unsigned short* xb    = (unsigned short*)alloc((size_t)N_NODES * DIM * 2);
    unsigned short* meanb = (unsigned short*)alloc((size_t)N_NODES * DIM * 2);
    unsigned short* h1b   = (unsigned short*)alloc((size_t)N_NODES * DIM * 2);
    unsigned short* h2b   = (unsigned short*)alloc((size_t)N_NODES * DIM * 2);
    unsigned char*  h8    = (unsigned char*)alloc((size_t)N_NODES * DIM);
    unsigned short* wb1 = (unsigned short*)alloc((size_t)DIM * 256 * 2);
    unsigned short* wb2 = (unsigned short*)alloc((size_t)DIM * 256 * 2);
    unsigned short* wb3 = (unsigned short*)alloc((size_t)48 * 256 * 2);

    // conversions (x -> bf16 + fp8 fused)
    k_xcvt<<<N_NODES * DIM / 8 / 256, 256, 0, stream>>>(x, xb, (unsigned int*)h8);
    k_wcvt<<<DIM, 256, 0, stream>>>(ws1, wn1, wb1, DIM);
    k_wcvt<<<DIM, 256, 0, stream>>>(ws2, wn2, wb2, DIM);
    k_wcvt<<<48,  256, 0, stream>>>(ws3, wn3, wb3, OUTD);

    // CSR build, binned (ws re-poisoned every call -> rebuild every call)
    hipMemsetAsync(deg, 0, (size_t)N_NODES * 4, stream);
    k_count<<<(N_EDGES + 255) / 256, 256, 0, stream>>>(dst, deg);
    k_bsum<<<NB_SCAN, 256, 0, stream>>>(deg, bsum);
    k_scanb<<<1, 256, 0, stream>>>(bsum, boff, row_ptr);
    k_scatter<<<NB_SCAN, 256, 0, stream>>>(deg, boff, row_ptr);
    k_scanbkt<<<1, 256, 0, stream>>>(bsum, boffB, gcur);
    k_bin<<<NBIN, 256, 0, stream>>>(src, dst, gcur, packed);
    k_place<<<NBK, 256, 0, stream>>>(packed, boffB, bsum, row_ptr, srcs);

    const int GB = (N_NODES + 63) / 64;

    // layer 1
    k_agg8<<<N_NODES / 4, 256, 0, stream>>>(h8, row_ptr, srcs, meanb);
    k_gemm_mfma<8, true, true><<<GB, 256, 0, stream>>>(xb, meanb, wb1, b1, h1b, h8, DIM);
    // layer 2 (agg reads h8 written by layer-1 gemm)
    k_agg8<<<N_NODES / 4, 256, 0, stream>>>(h8, row_ptr, srcs, meanb);
    k_gemm_mfma<8, true, true><<<GB, 256, 0, stream>>>(h1b, meanb, wb2, b2, h2b, h8, DIM);
    // layer 3
    k_agg8<<<N_NODES / 4, 256, 0, stream>>>(h8, row_ptr, srcs, meanb);
    k_gemm_mfma<3, false, false><<<GB, 256, 0, stream>>>(h2b, meanb, wb3, b3, d_out, nullptr, OUTD);
}

// Round 8
// 362.626 us; speedup vs baseline: 2.2548x; 1.0188x over previous
//
#include <hip/hip_runtime.h>

#define N_NODES 50000
#define N_EDGES 800000
#define DIM 128
#define OUTD 47
#define NB_SCAN ((N_NODES + 255) / 256) // 196 (row_ptr scan blocks == dst buckets)
#define NBK 196                         // dst buckets of 256 nodes
#define EPB 4096                        // edges per k_bin block
#define NBIN ((N_EDGES + EPB - 1) / EPB) // 196

typedef __attribute__((ext_vector_type(8))) short v8s;
typedef __attribute__((ext_vector_type(8))) unsigned short v8u;
typedef __attribute__((ext_vector_type(4))) float v4f;
typedef __attribute__((ext_vector_type(2))) float v2f;

static __device__ __forceinline__ unsigned short f2bf(float f) {
    union { float f; unsigned int u; } v; v.f = f;
    unsigned int x = v.u;
    return (unsigned short)((x + 0x7fffu + ((x >> 16) & 1u)) >> 16); // RNE
}
static __device__ __forceinline__ unsigned char f2fp8(float f) {
    unsigned int pk = __builtin_amdgcn_cvt_pk_fp8_f32(f, f, 0, false);
    return (unsigned char)(pk & 0xffu);
}

// ---------------- CSR build ----------------
// deg-only atomics (round-6 lesson: 196-bucket global histogram = 473 us of contention)
__global__ void k_count(const int* __restrict__ dst, int* __restrict__ deg) {
    int e = blockIdx.x * 256 + threadIdx.x;
    if (e < N_EDGES) atomicAdd(&deg[dst[e]], 1);
}

__global__ __launch_bounds__(256) void k_bsum(const int* __restrict__ deg,
                                              int* __restrict__ bsum) {
    __shared__ int s[256];
    int i = blockIdx.x * 256 + threadIdx.x;
    int v = (i < N_NODES) ? deg[i] : 0;
    s[threadIdx.x] = v;
    __syncthreads();
    for (int off = 128; off > 0; off >>= 1) {
        if (threadIdx.x < off) s[threadIdx.x] += s[threadIdx.x + off];
        __syncthreads();
    }
    if (threadIdx.x == 0) bsum[blockIdx.x] = s[0];
}

// one scan serves both row_ptr blocks and dst buckets (identical partition)
__global__ __launch_bounds__(256) void k_scans(const int* __restrict__ bsum,
                                               int* __restrict__ boff,
                                               int* __restrict__ gcur,
                                               int* __restrict__ row_ptr) {
    __shared__ int s[256];
    int t = threadIdx.x;
    int v = (t < NB_SCAN) ? bsum[t] : 0;
    s[t] = v;
    __syncthreads();
    for (int off = 1; off < 256; off <<= 1) {
        int u = (t >= off) ? s[t - off] : 0;
        __syncthreads();
        s[t] += u;
        __syncthreads();
    }
    if (t < NB_SCAN) { int ex = s[t] - v; boff[t] = ex; gcur[t] = ex; }
    if (t == 255) row_ptr[N_NODES] = s[255];
}

__global__ __launch_bounds__(256) void k_scatter(const int* __restrict__ deg,
                                                 const int* __restrict__ boff,
                                                 int* __restrict__ row_ptr) {
    __shared__ int s[256];
    int t = threadIdx.x;
    int i = blockIdx.x * 256 + t;
    int v = (i < N_NODES) ? deg[i] : 0;
    s[t] = v;
    __syncthreads();
    for (int off = 1; off < 256; off <<= 1) {
        int u = (t >= off) ? s[t - off] : 0;
        __syncthreads();
        s[t] += u;
        __syncthreads();
    }
    if (i < N_NODES) row_ptr[i] = s[t] - v + boff[blockIdx.x];
}

// bin edges by dst>>8 into bucket-contiguous packed runs (src<<8 | dst&255)
__global__ __launch_bounds__(256) void k_bin(const int* __restrict__ src,
                                             const int* __restrict__ dst,
                                             int* __restrict__ gcur,
                                             unsigned int* __restrict__ packed) {
    __shared__ int hist[NBK], gbase[NBK], cnt[NBK];
    int t = threadIdx.x;
    for (int i = t; i < NBK; i += 256) { hist[i] = 0; cnt[i] = 0; }
    __syncthreads();
    const int e0 = blockIdx.x * EPB;
    const int ecnt = min(EPB, N_EDGES - e0);
    for (int r = t; r < ecnt; r += 256)
        atomicAdd(&hist[dst[e0 + r] >> 8], 1); // LDS atomics, 196-way spread
    __syncthreads();
    if (t < NBK) gbase[t] = atomicAdd(&gcur[t], hist[t]); // 1 global atomic/bucket
    __syncthreads();
    for (int r = t; r < ecnt; r += 256) {
        int s = src[e0 + r], d = dst[e0 + r];
        int b = d >> 8;
        int loc = atomicAdd(&cnt[b], 1);
        packed[gbase[b] + loc] = ((unsigned int)s << 8) | (unsigned int)(d & 255);
    }
}

// per-bucket placement: one block owns one bucket's 256 dst nodes + its packed run
__global__ __launch_bounds__(256) void k_place(const unsigned int* __restrict__ packed,
                                               const int* __restrict__ boffB,
                                               const int* __restrict__ bsum,
                                               const int* __restrict__ row_ptr,
                                               int* __restrict__ src_sorted) {
    __shared__ int cur[256];
    const int b = blockIdx.x, t = threadIdx.x;
    int node = b * 256 + t;
    cur[t] = (node < N_NODES) ? row_ptr[node] : 0;
    __syncthreads();
    const int base = boffB[b], cb = bsum[b];
    for (int i = t; i < cb; i += 256) {
        unsigned int pkt = packed[base + i];
        int pos = atomicAdd(&cur[pkt & 255u], 1);
        src_sorted[pos] = (int)(pkt >> 8);
    }
}

// ---------------- x -> bf16 + fp8 (fused) ----------------
__global__ __launch_bounds__(256) void k_xcvt(const float* __restrict__ x,
                                              unsigned short* __restrict__ xb,
                                              unsigned int* __restrict__ x8) {
    int i = blockIdx.x * 256 + threadIdx.x; // 8 elems per thread
    float4 v0 = ((const float4*)x)[i * 2];
    float4 v1 = ((const float4*)x)[i * 2 + 1];
    ushort4 o0, o1;
    o0.x = f2bf(v0.x); o0.y = f2bf(v0.y); o0.z = f2bf(v0.z); o0.w = f2bf(v0.w);
    o1.x = f2bf(v1.x); o1.y = f2bf(v1.y); o1.z = f2bf(v1.z); o1.w = f2bf(v1.w);
    ((ushort4*)xb)[i * 2] = o0;
    ((ushort4*)xb)[i * 2 + 1] = o1;
    unsigned int a = __builtin_amdgcn_cvt_pk_fp8_f32(v0.x, v0.y, 0, false);
    a = __builtin_amdgcn_cvt_pk_fp8_f32(v0.z, v0.w, a, true);
    unsigned int b = __builtin_amdgcn_cvt_pk_fp8_f32(v1.x, v1.y, 0, false);
    b = __builtin_amdgcn_cvt_pk_fp8_f32(v1.z, v1.w, b, true);
    uint2 o; o.x = a; o.y = b;
    ((uint2*)x8)[i] = o;
}

__global__ void k_wcvt(const float* __restrict__ wself, const float* __restrict__ wneigh,
                       unsigned short* __restrict__ out, int J) {
    int idx = blockIdx.x * 256 + threadIdx.x;
    int j = idx >> 8, k = idx & 255;
    float v = 0.f;
    if (j < J) v = (k < DIM) ? wself[j * DIM + k] : wneigh[j * DIM + (k - DIM)];
    out[idx] = f2bf(v);
}

// ---------------- mean aggregation: 4 edges x 16 lanes, uint2 (8 fp8) per lane ----------------
// lane = es*16 + g: edge-slot es in [0,4), feature group g holds feats g*8..g*8+7.
// Butterfly shfl_xor(16,32) reduces edge-slots; lanes 0..15 store 16B bf16 each.
__global__ __launch_bounds__(256) void k_agg8(const unsigned char* __restrict__ h8,
                                              const int* __restrict__ row_ptr,
                                              const int* __restrict__ srcs,
                                              unsigned short* __restrict__ meanb) {
    const int wv = threadIdx.x >> 6;
    const int lane = threadIdx.x & 63;
    const int n = blockIdx.x * 4 + wv;
    const int g = lane & 15;
    const int es = lane >> 4;
    const int start = row_ptr[n], end = row_ptr[n + 1]; // wave-uniform
    float a0=0.f,a1=0.f,a2=0.f,a3=0.f,a4=0.f,a5=0.f,a6=0.f,a7=0.f;
    for (int e0 = start; e0 < end; e0 += 4) {
        int e = e0 + es;
        if (e < end) {
            int s = srcs[e];
            uint2 u = *(const uint2*)(h8 + (size_t)s * DIM + g * 8);
            v2f f01 = __builtin_amdgcn_cvt_pk_f32_fp8(u.x, false);
            v2f f23 = __builtin_amdgcn_cvt_pk_f32_fp8(u.x, true);
            v2f f45 = __builtin_amdgcn_cvt_pk_f32_fp8(u.y, false);
            v2f f67 = __builtin_amdgcn_cvt_pk_f32_fp8(u.y, true);
            a0 += f01[0]; a1 += f01[1]; a2 += f23[0]; a3 += f23[1];
            a4 += f45[0]; a5 += f45[1]; a6 += f67[0]; a7 += f67[1];
        }
    }
    a0 += __shfl_xor(a0, 16); a0 += __shfl_xor(a0, 32);
    a1 += __shfl_xor(a1, 16); a1 += __shfl_xor(a1, 32);
    a2 += __shfl_xor(a2, 16); a2 += __shfl_xor(a2, 32);
    a3 += __shfl_xor(a3, 16); a3 += __shfl_xor(a3, 32);
    a4 += __shfl_xor(a4, 16); a4 += __shfl_xor(a4, 32);
    a5 += __shfl_xor(a5, 16); a5 += __shfl_xor(a5, 32);
    a6 += __shfl_xor(a6, 16); a6 += __shfl_xor(a6, 32);
    a7 += __shfl_xor(a7, 16); a7 += __shfl_xor(a7, 32);
    if (lane < 16) {
        int d = end - start;
        float inv = (d > 0) ? 1.f / (float)d : 0.f;
        v8u o;
        o[0]=f2bf(a0*inv); o[1]=f2bf(a1*inv); o[2]=f2bf(a2*inv); o[3]=f2bf(a3*inv);
        o[4]=f2bf(a4*inv); o[5]=f2bf(a5*inv); o[6]=f2bf(a6*inv); o[7]=f2bf(a7*inv);
        *(v8u*)(meanb + (size_t)n * DIM + g * 8) = o;
    }
}

// ---------------- MFMA GEMM: 4 waves share one 16-node strip, tiles split across waves ----------------
// TPW tiles per wave; wave wv owns tiles wv*TPW..; grid = N_NODES/16 blocks -> 12.5k waves.
template <int TPW, int NTOT, bool RELU, bool OUTBF>
__global__ __launch_bounds__(256) void k_gemm_mfma(const unsigned short* __restrict__ Ab,
                                                   const unsigned short* __restrict__ Mb,
                                                   const unsigned short* __restrict__ Wb,
                                                   const float* __restrict__ bias,
                                                   void* __restrict__ out,
                                                   unsigned char* __restrict__ out8,
                                                   int outdim) {
    const int lane = threadIdx.x & 63;
    const int wv = threadIdx.x >> 6;
    const int m0 = blockIdx.x * 16; // grid is exactly N_NODES/16
    const int m = lane & 15, qd = lane >> 4;
    const int t0 = wv * TPW;
    const bool active = (t0 < NTOT); // layer 3: wave 3 idle
    const unsigned short* __restrict__ arow = Ab + (size_t)(m0 + m) * DIM;
    const unsigned short* __restrict__ mrow = Mb + (size_t)(m0 + m) * DIM;

    v4f acc[TPW] = {};
    if (active) {
        #pragma unroll
        for (int c = 0; c < 8; ++c) {
            const unsigned short* __restrict__ srow = (c < 4) ? arow : mrow;
            v8s af = *(const v8s*)(srow + (c & 3) * 32 + qd * 8);
            const int kglob = c * 32 + qd * 8;
            #pragma unroll
            for (int tt = 0; tt < TPW; ++tt) {
                v8s wf = *(const v8s*)(Wb + (size_t)((t0 + tt) * 16 + m) * 256 + kglob);
                acc[tt] = __builtin_amdgcn_mfma_f32_16x16x32_bf16(af, wf, acc[tt], 0, 0, 0);
            }
        }
        #pragma unroll
        for (int tt = 0; tt < TPW; ++tt) {
            int col = (t0 + tt) * 16 + m;
            bool colok = (col < outdim);
            float bv = colok ? bias[col] : 0.f;
            #pragma unroll
            for (int r = 0; r < 4; ++r) {
                int nrow = m0 + qd * 4 + r;
                if (colok) {
                    float v = acc[tt][r] + bv;
                    if (RELU) v = fmaxf(v, 0.f);
                    size_t idx = (size_t)nrow * outdim + col;
                    if (OUTBF) {
                        ((unsigned short*)out)[idx] = f2bf(v);
                        out8[idx] = f2fp8(v);
                    } else {
                        ((float*)out)[idx] = v;
                    }
                }
            }
        }
    }
}

extern "C" void kernel_launch(void* const* d_in, const int* in_sizes, int n_in,
                              void* d_out, int out_size, void* d_ws, size_t ws_size,
                              hipStream_t stream) {
    const float* x   = (const float*)d_in[0];
    const int*   src = (const int*)d_in[1];
    const int*   dst = (const int*)d_in[2];
    const float* ws1 = (const float*)d_in[3];
    const float* wn1 = (const float*)d_in[4];
    const float* b1  = (const float*)d_in[5];
    const float* ws2 = (const float*)d_in[6];
    const float* wn2 = (const float*)d_in[7];
    const float* b2  = (const float*)d_in[8];
    const float* ws3 = (const float*)d_in[9];
    const float* wn3 = (const float*)d_in[10];
    const float* b3  = (const float*)d_in[11];

    char* p = (char*)d_ws;
    auto alloc = [&](size_t bytes) { char* r = p; p += (bytes + 255) & ~(size_t)255; return r; };
    int*   deg     = (int*)alloc((size_t)N_NODES * 4);
    int*   row_ptr = (int*)alloc((size_t)(N_NODES + 1) * 4);
    int*   srcs    = (int*)alloc((size_t)N_EDGES * 4);
    unsigned int* packed = (unsigned int*)alloc((size_t)N_EDGES * 4);
    int*   bsum    = (int*)alloc((size_t)NB_SCAN * 4);
    int*   boff    = (int*)alloc((size_t)NB_SCAN * 4);
    int*   gcur    = (int*)alloc((size_t)NBK * 4);
    unsigned short* xb    = (unsigned short*)alloc((size_t)N_NODES * DIM * 2);
    unsigned short* meanb = (unsigned short*)alloc((size_t)N_NODES * DIM * 2);
    unsigned short* h1b   = (unsigned short*)alloc((size_t)N_NODES * DIM * 2);
    unsigned short* h2b   = (unsigned short*)alloc((size_t)N_NODES * DIM * 2);
    unsigned char*  h8    = (unsigned char*)alloc((size_t)N_NODES * DIM);
    unsigned short* wb1 = (unsigned short*)alloc((size_t)DIM * 256 * 2);
    unsigned short* wb2 = (unsigned short*)alloc((size_t)DIM * 256 * 2);
    unsigned short* wb3 = (unsigned short*)alloc((size_t)48 * 256 * 2);

    // conversions (x -> bf16 + fp8 fused)
    k_xcvt<<<N_NODES * DIM / 8 / 256, 256, 0, stream>>>(x, xb, (unsigned int*)h8);
    k_wcvt<<<DIM, 256, 0, stream>>>(ws1, wn1, wb1, DIM);
    k_wcvt<<<DIM, 256, 0, stream>>>(ws2, wn2, wb2, DIM);
    k_wcvt<<<48,  256, 0, stream>>>(ws3, wn3, wb3, OUTD);

    // CSR build, binned
    hipMemsetAsync(deg, 0, (size_t)N_NODES * 4, stream);
    k_count<<<(N_EDGES + 255) / 256, 256, 0, stream>>>(dst, deg);
    k_bsum<<<NB_SCAN, 256, 0, stream>>>(deg, bsum);
    k_scans<<<1, 256, 0, stream>>>(bsum, boff, gcur, row_ptr);
    k_scatter<<<NB_SCAN, 256, 0, stream>>>(deg, boff, row_ptr);
    k_bin<<<NBIN, 256, 0, stream>>>(src, dst, gcur, packed);
    k_place<<<NBK, 256, 0, stream>>>(packed, boff, bsum, row_ptr, srcs);

    const int GB = N_NODES / 16; // 3125 blocks, 4 waves share 16 nodes

    // layer 1
    k_agg8<<<N_NODES / 4, 256, 0, stream>>>(h8, row_ptr, srcs, meanb);
    k_gemm_mfma<2, 8, true, true><<<GB, 256, 0, stream>>>(xb, meanb, wb1, b1, h1b, h8, DIM);
    // layer 2 (agg reads h8 written by layer-1 gemm)
    k_agg8<<<N_NODES / 4, 256, 0, stream>>>(h8, row_ptr, srcs, meanb);
    k_gemm_mfma<2, 8, true, true><<<GB, 256, 0, stream>>>(h1b, meanb, wb2, b2, h2b, h8, DIM);
    // layer 3
    k_agg8<<<N_NODES / 4, 256, 0, stream>>>(h8, row_ptr, srcs, meanb);
    k_gemm_mfma<1, 3, false, false><<<GB, 256, 0, stream>>>(h2b, meanb, wb3, b3, d_out, nullptr, OUTD);
}

// Round 9
// 330.587 us; speedup vs baseline: 2.4733x; 1.0969x over previous
//
#include <hip/hip_runtime.h>

#define N_NODES 50000
#define N_EDGES 800000
#define DIM 128
#define OUTD 47
#define NB_SCAN ((N_NODES + 255) / 256) // 196 (row_ptr scan blocks == dst buckets)
#define NBK 196                         // dst buckets of 256 nodes
#define EPB 4096                        // edges per k_bin block
#define NBIN ((N_EDGES + EPB - 1) / EPB) // 196

typedef __attribute__((ext_vector_type(8))) short v8s;
typedef __attribute__((ext_vector_type(8))) unsigned short v8u;
typedef __attribute__((ext_vector_type(4))) float v4f;
typedef __attribute__((ext_vector_type(2))) float v2f;

static __device__ __forceinline__ unsigned short f2bf(float f) {
    union { float f; unsigned int u; } v; v.f = f;
    unsigned int x = v.u;
    return (unsigned short)((x + 0x7fffu + ((x >> 16) & 1u)) >> 16); // RNE
}
static __device__ __forceinline__ unsigned char f2fp8(float f) {
    unsigned int pk = __builtin_amdgcn_cvt_pk_fp8_f32(f, f, 0, false);
    return (unsigned char)(pk & 0xffu);
}

// ---------------- CSR build ----------------
// deg-only atomics (round-6 lesson: 196-bucket global histogram = 473 us of contention)
__global__ void k_count(const int* __restrict__ dst, int* __restrict__ deg) {
    int e = blockIdx.x * 256 + threadIdx.x;
    if (e < N_EDGES) atomicAdd(&deg[dst[e]], 1);
}

__global__ __launch_bounds__(256) void k_bsum(const int* __restrict__ deg,
                                              int* __restrict__ bsum) {
    __shared__ int s[256];
    int i = blockIdx.x * 256 + threadIdx.x;
    int v = (i < N_NODES) ? deg[i] : 0;
    s[threadIdx.x] = v;
    __syncthreads();
    for (int off = 128; off > 0; off >>= 1) {
        if (threadIdx.x < off) s[threadIdx.x] += s[threadIdx.x + off];
        __syncthreads();
    }
    if (threadIdx.x == 0) bsum[blockIdx.x] = s[0];
}

// one scan serves both row_ptr blocks and dst buckets (identical partition)
__global__ __launch_bounds__(256) void k_scans(const int* __restrict__ bsum,
                                               int* __restrict__ boff,
                                               int* __restrict__ gcur,
                                               int* __restrict__ row_ptr) {
    __shared__ int s[256];
    int t = threadIdx.x;
    int v = (t < NB_SCAN) ? bsum[t] : 0;
    s[t] = v;
    __syncthreads();
    for (int off = 1; off < 256; off <<= 1) {
        int u = (t >= off) ? s[t - off] : 0;
        __syncthreads();
        s[t] += u;
        __syncthreads();
    }
    if (t < NB_SCAN) { int ex = s[t] - v; boff[t] = ex; gcur[t] = ex; }
    if (t == 255) row_ptr[N_NODES] = s[255];
}

__global__ __launch_bounds__(256) void k_scatter(const int* __restrict__ deg,
                                                 const int* __restrict__ boff,
                                                 int* __restrict__ row_ptr) {
    __shared__ int s[256];
    int t = threadIdx.x;
    int i = blockIdx.x * 256 + t;
    int v = (i < N_NODES) ? deg[i] : 0;
    s[t] = v;
    __syncthreads();
    for (int off = 1; off < 256; off <<= 1) {
        int u = (t >= off) ? s[t - off] : 0;
        __syncthreads();
        s[t] += u;
        __syncthreads();
    }
    if (i < N_NODES) row_ptr[i] = s[t] - v + boff[blockIdx.x];
}

// bin edges by dst>>8 into bucket-contiguous packed runs (src<<8 | dst&255)
__global__ __launch_bounds__(256) void k_bin(const int* __restrict__ src,
                                             const int* __restrict__ dst,
                                             int* __restrict__ gcur,
                                             unsigned int* __restrict__ packed) {
    __shared__ int hist[NBK], gbase[NBK], cnt[NBK];
    int t = threadIdx.x;
    for (int i = t; i < NBK; i += 256) { hist[i] = 0; cnt[i] = 0; }
    __syncthreads();
    const int e0 = blockIdx.x * EPB;
    const int ecnt = min(EPB, N_EDGES - e0);
    for (int r = t; r < ecnt; r += 256)
        atomicAdd(&hist[dst[e0 + r] >> 8], 1); // LDS atomics, 196-way spread
    __syncthreads();
    if (t < NBK) gbase[t] = atomicAdd(&gcur[t], hist[t]); // 1 global atomic/bucket
    __syncthreads();
    for (int r = t; r < ecnt; r += 256) {
        int s = src[e0 + r], d = dst[e0 + r];
        int b = d >> 8;
        int loc = atomicAdd(&cnt[b], 1);
        packed[gbase[b] + loc] = ((unsigned int)s << 8) | (unsigned int)(d & 255);
    }
}

// per-bucket placement: one block owns one bucket's 256 dst nodes + its packed run
__global__ __launch_bounds__(256) void k_place(const unsigned int* __restrict__ packed,
                                               const int* __restrict__ boffB,
                                               const int* __restrict__ bsum,
                                               const int* __restrict__ row_ptr,
                                               int* __restrict__ src_sorted) {
    __shared__ int cur[256];
    const int b = blockIdx.x, t = threadIdx.x;
    int node = b * 256 + t;
    cur[t] = (node < N_NODES) ? row_ptr[node] : 0;
    __syncthreads();
    const int base = boffB[b], cb = bsum[b];
    for (int i = t; i < cb; i += 256) {
        unsigned int pkt = packed[base + i];
        int pos = atomicAdd(&cur[pkt & 255u], 1);
        src_sorted[pos] = (int)(pkt >> 8);
    }
}

// ---------------- x -> bf16 + fp8 (fused) ----------------
__global__ __launch_bounds__(256) void k_xcvt(const float* __restrict__ x,
                                              unsigned short* __restrict__ xb,
                                              unsigned int* __restrict__ x8) {
    int i = blockIdx.x * 256 + threadIdx.x; // 8 elems per thread
    float4 v0 = ((const float4*)x)[i * 2];
    float4 v1 = ((const float4*)x)[i * 2 + 1];
    ushort4 o0, o1;
    o0.x = f2bf(v0.x); o0.y = f2bf(v0.y); o0.z = f2bf(v0.z); o0.w = f2bf(v0.w);
    o1.x = f2bf(v1.x); o1.y = f2bf(v1.y); o1.z = f2bf(v1.z); o1.w = f2bf(v1.w);
    ((ushort4*)xb)[i * 2] = o0;
    ((ushort4*)xb)[i * 2 + 1] = o1;
    unsigned int a = __builtin_amdgcn_cvt_pk_fp8_f32(v0.x, v0.y, 0, false);
    a = __builtin_amdgcn_cvt_pk_fp8_f32(v0.z, v0.w, a, true);
    unsigned int b = __builtin_amdgcn_cvt_pk_fp8_f32(v1.x, v1.y, 0, false);
    b = __builtin_amdgcn_cvt_pk_fp8_f32(v1.z, v1.w, b, true);
    uint2 o; o.x = a; o.y = b;
    ((uint2*)x8)[i] = o;
}

__global__ void k_wcvt(const float* __restrict__ wself, const float* __restrict__ wneigh,
                       unsigned short* __restrict__ out, int J) {
    int idx = blockIdx.x * 256 + threadIdx.x;
    int j = idx >> 8, k = idx & 255;
    float v = 0.f;
    if (j < J) v = (k < DIM) ? wself[j * DIM + k] : wneigh[j * DIM + (k - DIM)];
    out[idx] = f2bf(v);
}

// ---------------- mean aggregation: 4 edges x 16 lanes, uint2 (8 fp8) per lane ----------------
__global__ __launch_bounds__(256) void k_agg8(const unsigned char* __restrict__ h8,
                                              const int* __restrict__ row_ptr,
                                              const int* __restrict__ srcs,
                                              unsigned short* __restrict__ meanb) {
    const int wv = threadIdx.x >> 6;
    const int lane = threadIdx.x & 63;
    const int n = blockIdx.x * 4 + wv;
    const int g = lane & 15;
    const int es = lane >> 4;
    const int start = row_ptr[n], end = row_ptr[n + 1]; // wave-uniform
    float a0=0.f,a1=0.f,a2=0.f,a3=0.f,a4=0.f,a5=0.f,a6=0.f,a7=0.f;
    for (int e0 = start; e0 < end; e0 += 4) {
        int e = e0 + es;
        if (e < end) {
            int s = srcs[e];
            uint2 u = *(const uint2*)(h8 + (size_t)s * DIM + g * 8);
            v2f f01 = __builtin_amdgcn_cvt_pk_f32_fp8(u.x, false);
            v2f f23 = __builtin_amdgcn_cvt_pk_f32_fp8(u.x, true);
            v2f f45 = __builtin_amdgcn_cvt_pk_f32_fp8(u.y, false);
            v2f f67 = __builtin_amdgcn_cvt_pk_f32_fp8(u.y, true);
            a0 += f01[0]; a1 += f01[1]; a2 += f23[0]; a3 += f23[1];
            a4 += f45[0]; a5 += f45[1]; a6 += f67[0]; a7 += f67[1];
        }
    }
    a0 += __shfl_xor(a0, 16); a0 += __shfl_xor(a0, 32);
    a1 += __shfl_xor(a1, 16); a1 += __shfl_xor(a1, 32);
    a2 += __shfl_xor(a2, 16); a2 += __shfl_xor(a2, 32);
    a3 += __shfl_xor(a3, 16); a3 += __shfl_xor(a3, 32);
    a4 += __shfl_xor(a4, 16); a4 += __shfl_xor(a4, 32);
    a5 += __shfl_xor(a5, 16); a5 += __shfl_xor(a5, 32);
    a6 += __shfl_xor(a6, 16); a6 += __shfl_xor(a6, 32);
    a7 += __shfl_xor(a7, 16); a7 += __shfl_xor(a7, 32);
    if (lane < 16) {
        int d = end - start;
        float inv = (d > 0) ? 1.f / (float)d : 0.f;
        v8u o;
        o[0]=f2bf(a0*inv); o[1]=f2bf(a1*inv); o[2]=f2bf(a2*inv); o[3]=f2bf(a3*inv);
        o[4]=f2bf(a4*inv); o[5]=f2bf(a5*inv); o[6]=f2bf(a6*inv); o[7]=f2bf(a7*inv);
        *(v8u*)(meanb + (size_t)n * DIM + g * 8) = o;
    }
}

// ---------------- LDS-staged MFMA GEMM (canonical §5 shape, whole K resident) ----------------
// Block: 64 nodes x JT feats, 256 threads. LDS: A 64x256 bf16 (32KB) + W JTx256 (24/32KB).
// XOR swizzle (koff ^ ((row&7)*8 shorts)) -> ds_read_b128 phases are 2-way/bank = free.
// Wave wv owns nodes wv*16..+16, all TPW=JT/16 j-tiles. Zero global loads in K-loop.
template <int JT, int TPW, bool RELU, bool OUTBF>
__global__ __launch_bounds__(256) void k_gemm_lds(const unsigned short* __restrict__ Ab,
                                                  const unsigned short* __restrict__ Mb,
                                                  const unsigned short* __restrict__ Wb,
                                                  const float* __restrict__ bias,
                                                  void* __restrict__ out,
                                                  unsigned char* __restrict__ out8,
                                                  int outdim) {
    __shared__ unsigned short Alds[64 * 256];  // 32 KB
    __shared__ unsigned short Wlds[JT * 256];  // 32 KB (JT=64) / 24 KB (JT=48)
    const int tid = threadIdx.x;
    const int m0 = blockIdx.x * 64;
    const int j0 = blockIdx.y * JT;
    // ---- stage A (concat [Ab row | Mb row], 32 chunks of 8 shorts per row) ----
    v8u ar[8];
    #pragma unroll
    for (int i = 0; i < 8; ++i) {
        int t = tid + 256 * i;
        int row = t >> 5, ch = t & 31;
        int node = m0 + row; if (node >= N_NODES) node = N_NODES - 1;
        const unsigned short* s = (ch < 16) ? (Ab + (size_t)node * DIM + ch * 8)
                                            : (Mb + (size_t)node * DIM + (ch - 16) * 8);
        ar[i] = *(const v8u*)s; // 8 loads in flight
    }
    constexpr int WI = (JT * 32 + 255) / 256;
    v8u wr[WI];
    #pragma unroll
    for (int i = 0; i < WI; ++i) {
        int t = tid + 256 * i;
        if (t < JT * 32) {
            int row = t >> 5, ch = t & 31;
            wr[i] = *(const v8u*)(Wb + (size_t)(j0 + row) * 256 + ch * 8);
        }
    }
    #pragma unroll
    for (int i = 0; i < 8; ++i) {
        int t = tid + 256 * i;
        int row = t >> 5, ch = t & 31;
        *(v8u*)(Alds + row * 256 + ((ch * 8) ^ ((row & 7) * 8))) = ar[i];
    }
    #pragma unroll
    for (int i = 0; i < WI; ++i) {
        int t = tid + 256 * i;
        if (t < JT * 32) {
            int row = t >> 5, ch = t & 31;
            *(v8u*)(Wlds + row * 256 + ((ch * 8) ^ ((row & 7) * 8))) = wr[i];
        }
    }
    __syncthreads();
    // ---- K-loop: pure LDS + MFMA ----
    const int lane = tid & 63, wv = tid >> 6;
    const int m = lane & 15, qd = lane >> 4;
    const int arow = wv * 16 + m;
    v4f acc[TPW] = {};
    #pragma unroll
    for (int c = 0; c < 8; ++c) {
        const int koff = c * 32 + qd * 8;
        v8s af = *(const v8s*)(Alds + arow * 256 + (koff ^ ((arow & 7) * 8)));
        #pragma unroll
        for (int t = 0; t < TPW; ++t) {
            int wrow = t * 16 + m;
            v8s wf = *(const v8s*)(Wlds + wrow * 256 + (koff ^ ((wrow & 7) * 8)));
            acc[t] = __builtin_amdgcn_mfma_f32_16x16x32_bf16(af, wf, acc[t], 0, 0, 0);
        }
    }
    // ---- epilogue: D col=lane&15 (feat), row=qd*4+r (node) ----
    #pragma unroll
    for (int t = 0; t < TPW; ++t) {
        int col = j0 + t * 16 + m;
        bool colok = (col < outdim);
        float bv = colok ? bias[col] : 0.f;
        #pragma unroll
        for (int r = 0; r < 4; ++r) {
            int nrow = m0 + wv * 16 + qd * 4 + r;
            if (colok && nrow < N_NODES) {
                float v = acc[t][r] + bv;
                if (RELU) v = fmaxf(v, 0.f);
                size_t idx = (size_t)nrow * outdim + col;
                if (OUTBF) {
                    ((unsigned short*)out)[idx] = f2bf(v);
                    out8[idx] = f2fp8(v);
                } else {
                    ((float*)out)[idx] = v;
                }
            }
        }
    }
}

extern "C" void kernel_launch(void* const* d_in, const int* in_sizes, int n_in,
                              void* d_out, int out_size, void* d_ws, size_t ws_size,
                              hipStream_t stream) {
    const float* x   = (const float*)d_in[0];
    const int*   src = (const int*)d_in[1];
    const int*   dst = (const int*)d_in[2];
    const float* ws1 = (const float*)d_in[3];
    const float* wn1 = (const float*)d_in[4];
    const float* b1  = (const float*)d_in[5];
    const float* ws2 = (const float*)d_in[6];
    const float* wn2 = (const float*)d_in[7];
    const float* b2  = (const float*)d_in[8];
    const float* ws3 = (const float*)d_in[9];
    const float* wn3 = (const float*)d_in[10];
    const float* b3  = (const float*)d_in[11];

    char* p = (char*)d_ws;
    auto alloc = [&](size_t bytes) { char* r = p; p += (bytes + 255) & ~(size_t)255; return r; };
    int*   deg     = (int*)alloc((size_t)N_NODES * 4);
    int*   row_ptr = (int*)alloc((size_t)(N_NODES + 1) * 4);
    int*   srcs    = (int*)alloc((size_t)N_EDGES * 4);
    unsigned int* packed = (unsigned int*)alloc((size_t)N_EDGES * 4);
    int*   bsum    = (int*)alloc((size_t)NB_SCAN * 4);
    int*   boff    = (int*)alloc((size_t)NB_SCAN * 4);
    int*   gcur    = (int*)alloc((size_t)NBK * 4);
    unsigned short* xb    = (unsigned short*)alloc((size_t)N_NODES * DIM * 2);
    unsigned short* meanb = (unsigned short*)alloc((size_t)N_NODES * DIM * 2);
    unsigned short* h1b   = (unsigned short*)alloc((size_t)N_NODES * DIM * 2);
    unsigned short* h2b   = (unsigned short*)alloc((size_t)N_NODES * DIM * 2);
    unsigned char*  h8    = (unsigned char*)alloc((size_t)N_NODES * DIM);
    unsigned short* wb1 = (unsigned short*)alloc((size_t)DIM * 256 * 2);
    unsigned short* wb2 = (unsigned short*)alloc((size_t)DIM * 256 * 2);
    unsigned short* wb3 = (unsigned short*)alloc((size_t)48 * 256 * 2);

    // conversions (x -> bf16 + fp8 fused)
    k_xcvt<<<N_NODES * DIM / 8 / 256, 256, 0, stream>>>(x, xb, (unsigned int*)h8);
    k_wcvt<<<DIM, 256, 0, stream>>>(ws1, wn1, wb1, DIM);
    k_wcvt<<<DIM, 256, 0, stream>>>(ws2, wn2, wb2, DIM);
    k_wcvt<<<48,  256, 0, stream>>>(ws3, wn3, wb3, OUTD);

    // CSR build, binned
    hipMemsetAsync(deg, 0, (size_t)N_NODES * 4, stream);
    k_count<<<(N_EDGES + 255) / 256, 256, 0, stream>>>(dst, deg);
    k_bsum<<<NB_SCAN, 256, 0, stream>>>(deg, bsum);
    k_scans<<<1, 256, 0, stream>>>(bsum, boff, gcur, row_ptr);
    k_scatter<<<NB_SCAN, 256, 0, stream>>>(deg, boff, row_ptr);
    k_bin<<<NBIN, 256, 0, stream>>>(src, dst, gcur, packed);
    k_place<<<NBK, 256, 0, stream>>>(packed, boff, bsum, row_ptr, srcs);

    const int MB = (N_NODES + 63) / 64; // 782 node-blocks of 64

    // layer 1
    k_agg8<<<N_NODES / 4, 256, 0, stream>>>(h8, row_ptr, srcs, meanb);
    k_gemm_lds<64, 4, true, true><<<dim3(MB, 2), 256, 0, stream>>>(xb, meanb, wb1, b1, h1b, h8, DIM);
    // layer 2 (agg reads h8 written by layer-1 gemm)
    k_agg8<<<N_NODES / 4, 256, 0, stream>>>(h8, row_ptr, srcs, meanb);
    k_gemm_lds<64, 4, true, true><<<dim3(MB, 2), 256, 0, stream>>>(h1b, meanb, wb2, b2, h2b, h8, DIM);
    // layer 3
    k_agg8<<<N_NODES / 4, 256, 0, stream>>>(h8, row_ptr, srcs, meanb);
    k_gemm_lds<48, 3, false, false><<<dim3(MB, 1), 256, 0, stream>>>(h2b, meanb, wb3, b3, d_out, nullptr, OUTD);
}

// Round 10
// 264.389 us; speedup vs baseline: 3.0925x; 1.2504x over previous
//
#include <hip/hip_runtime.h>

#define N_NODES 50000
#define N_EDGES 800000
#define DIM 128
#define OUTD 47
#define NBK 196                          // dst buckets of 256 nodes
#define EPB 4096                         // edges per histogram/bin block
#define NBIN ((N_EDGES + EPB - 1) / EPB) // 196
#define XCVT_NB (N_NODES * DIM / 8 / 256) // 3125 blocks, 8 elems/thread
#define WCVT_NB (DIM + DIM + 48)         // 304 weight-row blocks

typedef __attribute__((ext_vector_type(8))) short v8s;
typedef __attribute__((ext_vector_type(8))) unsigned short v8u;
typedef __attribute__((ext_vector_type(4))) float v4f;
typedef __attribute__((ext_vector_type(2))) float v2f;

static __device__ __forceinline__ unsigned short f2bf(float f) {
    union { float f; unsigned int u; } v; v.f = f;
    unsigned int x = v.u;
    return (unsigned short)((x + 0x7fffu + ((x >> 16) & 1u)) >> 16); // RNE
}
static __device__ __forceinline__ unsigned char f2fp8(float f) {
    unsigned int pk = __builtin_amdgcn_cvt_pk_fp8_f32(f, f, 0, false);
    return (unsigned char)(pk & 0xffu);
}

// ---------------- prep: x->bf16+fp8 | per-block bucket hist partials | weight cvt ----------------
// One kernel, three block ranges. No global atomics anywhere (round-6 lesson).
__global__ __launch_bounds__(256) void k_prep(const float* __restrict__ x,
                                              unsigned short* __restrict__ xb,
                                              unsigned int* __restrict__ x8,
                                              const int* __restrict__ dst,
                                              int* __restrict__ parts,
                                              const float* __restrict__ ws1, const float* __restrict__ wn1,
                                              const float* __restrict__ ws2, const float* __restrict__ wn2,
                                              const float* __restrict__ ws3, const float* __restrict__ wn3,
                                              unsigned short* __restrict__ wb1,
                                              unsigned short* __restrict__ wb2,
                                              unsigned short* __restrict__ wb3) {
    __shared__ int hist[NBK];
    const int bx = blockIdx.x, tid = threadIdx.x;
    if (bx < XCVT_NB) {
        int i = bx * 256 + tid; // 8 elems per thread
        float4 v0 = ((const float4*)x)[i * 2];
        float4 v1 = ((const float4*)x)[i * 2 + 1];
        ushort4 o0, o1;
        o0.x = f2bf(v0.x); o0.y = f2bf(v0.y); o0.z = f2bf(v0.z); o0.w = f2bf(v0.w);
        o1.x = f2bf(v1.x); o1.y = f2bf(v1.y); o1.z = f2bf(v1.z); o1.w = f2bf(v1.w);
        ((ushort4*)xb)[i * 2] = o0;
        ((ushort4*)xb)[i * 2 + 1] = o1;
        unsigned int a = __builtin_amdgcn_cvt_pk_fp8_f32(v0.x, v0.y, 0, false);
        a = __builtin_amdgcn_cvt_pk_fp8_f32(v0.z, v0.w, a, true);
        unsigned int b = __builtin_amdgcn_cvt_pk_fp8_f32(v1.x, v1.y, 0, false);
        b = __builtin_amdgcn_cvt_pk_fp8_f32(v1.z, v1.w, b, true);
        uint2 o; o.x = a; o.y = b;
        ((uint2*)x8)[i] = o;
    } else if (bx < XCVT_NB + NBIN) {
        const int j = bx - XCVT_NB;
        for (int i = tid; i < NBK; i += 256) hist[i] = 0;
        __syncthreads();
        const int e0 = j * EPB;
        const int ecnt = min(EPB, N_EDGES - e0);
        for (int r = tid; r < ecnt; r += 256)
            atomicAdd(&hist[dst[e0 + r] >> 8], 1); // LDS only
        __syncthreads();
        for (int i = tid; i < NBK; i += 256) parts[j * NBK + i] = hist[i];
    } else {
        int b2 = bx - XCVT_NB - NBIN; // weight row
        const float *sw, *nw; unsigned short* ob; int j, J;
        if (b2 < DIM)            { sw = ws1; nw = wn1; ob = wb1; j = b2;            J = DIM; }
        else if (b2 < 2 * DIM)   { sw = ws2; nw = wn2; ob = wb2; j = b2 - DIM;      J = DIM; }
        else                     { sw = ws3; nw = wn3; ob = wb3; j = b2 - 2 * DIM;  J = OUTD; }
        int k = tid;
        float v = 0.f;
        if (j < J) v = (k < DIM) ? sw[j * DIM + k] : nw[j * DIM + (k - DIM)];
        ob[j * 256 + k] = f2bf(v);
    }
}

// ---------------- scan2: bucket totals, boffB, exact per-(block,bucket) bases ----------------
__global__ __launch_bounds__(256) void k_scan2(const int* __restrict__ parts,
                                               int* __restrict__ gbase,
                                               int* __restrict__ boffB,
                                               int* __restrict__ btot,
                                               int* __restrict__ row_ptr) {
    __shared__ int s[256];
    const int t = threadIdx.x;
    int tot = 0;
    if (t < NBK)
        for (int i = 0; i < NBIN; ++i) tot += parts[i * NBK + t];
    s[t] = tot;
    __syncthreads();
    for (int off = 1; off < 256; off <<= 1) {
        int u = (t >= off) ? s[t - off] : 0;
        __syncthreads();
        s[t] += u;
        __syncthreads();
    }
    if (t < NBK) {
        int run = s[t] - tot; // exclusive bucket base
        boffB[t] = run; btot[t] = tot;
        for (int i = 0; i < NBIN; ++i) {
            gbase[i * NBK + t] = run;
            run += parts[i * NBK + t];
        }
    }
    if (t == 255) row_ptr[N_NODES] = s[255]; // == N_EDGES
}

// ---------------- bin: place edges at precomputed bases (no global atomics) ----------------
__global__ __launch_bounds__(256) void k_bin(const int* __restrict__ src,
                                             const int* __restrict__ dst,
                                             const int* __restrict__ gbase,
                                             unsigned int* __restrict__ packed) {
    __shared__ int gb[NBK], cnt[NBK];
    const int t = threadIdx.x;
    for (int i = t; i < NBK; i += 256) { gb[i] = gbase[blockIdx.x * NBK + i]; cnt[i] = 0; }
    __syncthreads();
    const int e0 = blockIdx.x * EPB;
    const int ecnt = min(EPB, N_EDGES - e0);
    for (int r = t; r < ecnt; r += 256) {
        int s = src[e0 + r], d = dst[e0 + r];
        int b = d >> 8;
        int loc = atomicAdd(&cnt[b], 1); // LDS
        packed[gb[b] + loc] = ((unsigned int)s << 8) | (unsigned int)(d & 255);
    }
}

// ---------------- place: local hist -> row_ptr for own 256 nodes, scatter src_sorted ----------------
__global__ __launch_bounds__(256) void k_place(const unsigned int* __restrict__ packed,
                                               const int* __restrict__ boffB,
                                               const int* __restrict__ btot,
                                               int* __restrict__ row_ptr,
                                               int* __restrict__ src_sorted) {
    __shared__ int hist[256], cur[256], s[256];
    const int b = blockIdx.x, t = threadIdx.x;
    hist[t] = 0;
    __syncthreads();
    const int base = boffB[b], cb = btot[b];
    for (int i = t; i < cb; i += 256)
        atomicAdd(&hist[packed[base + i] & 255u], 1); // LDS, ~16 avg per counter
    __syncthreads();
    int v = hist[t];
    s[t] = v;
    __syncthreads();
    for (int off = 1; off < 256; off <<= 1) {
        int u = (t >= off) ? s[t - off] : 0;
        __syncthreads();
        s[t] += u;
        __syncthreads();
    }
    int excl = base + s[t] - v;
    int node = b * 256 + t;
    if (node < N_NODES) row_ptr[node] = excl;
    cur[t] = excl;
    __syncthreads();
    for (int i = t; i < cb; i += 256) {
        unsigned int pkt = packed[base + i];
        int pos = atomicAdd(&cur[pkt & 255u], 1);
        src_sorted[pos] = (int)(pkt >> 8); // lands in this bucket's ~16KB region
    }
}

// ---------------- mean aggregation: 4 nodes/wave, 16 lanes/node, no shuffles ----------------
// lane = ns*16 + g: node-slot ns owns node (blk*16 + wv*4 + ns); lane holds feats g*8..g*8+7.
// All 64 lanes accumulate + store (1KB coalesced per wave).
__global__ __launch_bounds__(256) void k_agg8(const unsigned char* __restrict__ h8,
                                              const int* __restrict__ row_ptr,
                                              const int* __restrict__ srcs,
                                              unsigned short* __restrict__ meanb) {
    const int tid = threadIdx.x;
    const int lane = tid & 63, wv = tid >> 6;
    const int g = lane & 15, ns = lane >> 4;
    const int n = blockIdx.x * 16 + wv * 4 + ns;
    const int start = row_ptr[n], end = row_ptr[n + 1]; // uniform per 16-lane group
    float a0=0.f,a1=0.f,a2=0.f,a3=0.f,a4=0.f,a5=0.f,a6=0.f,a7=0.f;
    int e = start;
    for (; e + 2 <= end; e += 2) {
        int s0 = srcs[e], s1 = srcs[e + 1];
        uint2 u0 = *(const uint2*)(h8 + (size_t)s0 * DIM + g * 8);
        uint2 u1 = *(const uint2*)(h8 + (size_t)s1 * DIM + g * 8);
        v2f p0 = __builtin_amdgcn_cvt_pk_f32_fp8(u0.x, false);
        v2f p1 = __builtin_amdgcn_cvt_pk_f32_fp8(u0.x, true);
        v2f p2 = __builtin_amdgcn_cvt_pk_f32_fp8(u0.y, false);
        v2f p3 = __builtin_amdgcn_cvt_pk_f32_fp8(u0.y, true);
        v2f q0 = __builtin_amdgcn_cvt_pk_f32_fp8(u1.x, false);
        v2f q1 = __builtin_amdgcn_cvt_pk_f32_fp8(u1.x, true);
        v2f q2 = __builtin_amdgcn_cvt_pk_f32_fp8(u1.y, false);
        v2f q3 = __builtin_amdgcn_cvt_pk_f32_fp8(u1.y, true);
        a0 += p0[0] + q0[0]; a1 += p0[1] + q0[1];
        a2 += p1[0] + q1[0]; a3 += p1[1] + q1[1];
        a4 += p2[0] + q2[0]; a5 += p2[1] + q2[1];
        a6 += p3[0] + q3[0]; a7 += p3[1] + q3[1];
    }
    if (e < end) {
        int s0 = srcs[e];
        uint2 u0 = *(const uint2*)(h8 + (size_t)s0 * DIM + g * 8);
        v2f p0 = __builtin_amdgcn_cvt_pk_f32_fp8(u0.x, false);
        v2f p1 = __builtin_amdgcn_cvt_pk_f32_fp8(u0.x, true);
        v2f p2 = __builtin_amdgcn_cvt_pk_f32_fp8(u0.y, false);
        v2f p3 = __builtin_amdgcn_cvt_pk_f32_fp8(u0.y, true);
        a0 += p0[0]; a1 += p0[1]; a2 += p1[0]; a3 += p1[1];
        a4 += p2[0]; a5 += p2[1]; a6 += p3[0]; a7 += p3[1];
    }
    int d = end - start;
    float inv = (d > 0) ? 1.f / (float)d : 0.f;
    v8u o;
    o[0]=f2bf(a0*inv); o[1]=f2bf(a1*inv); o[2]=f2bf(a2*inv); o[3]=f2bf(a3*inv);
    o[4]=f2bf(a4*inv); o[5]=f2bf(a5*inv); o[6]=f2bf(a6*inv); o[7]=f2bf(a7*inv);
    *(v8u*)(meanb + (size_t)n * DIM + g * 8) = o;
}

// ---------------- LDS-staged MFMA GEMM (whole K resident, XOR-swizzled) ----------------
template <int JT, int TPW, bool RELU, bool OUTBF>
__global__ __launch_bounds__(256) void k_gemm_lds(const unsigned short* __restrict__ Ab,
                                                  const unsigned short* __restrict__ Mb,
                                                  const unsigned short* __restrict__ Wb,
                                                  const float* __restrict__ bias,
                                                  void* __restrict__ out,
                                                  unsigned char* __restrict__ out8,
                                                  int outdim) {
    __shared__ unsigned short Alds[64 * 256];  // 32 KB
    __shared__ unsigned short Wlds[JT * 256];  // 32 KB (JT=64) / 24 KB (JT=48)
    const int tid = threadIdx.x;
    const int m0 = blockIdx.x * 64;
    const int j0 = blockIdx.y * JT;
    v8u ar[8];
    #pragma unroll
    for (int i = 0; i < 8; ++i) {
        int t = tid + 256 * i;
        int row = t >> 5, ch = t & 31;
        int node = m0 + row; if (node >= N_NODES) node = N_NODES - 1;
        const unsigned short* s = (ch < 16) ? (Ab + (size_t)node * DIM + ch * 8)
                                            : (Mb + (size_t)node * DIM + (ch - 16) * 8);
        ar[i] = *(const v8u*)s;
    }
    constexpr int WI = (JT * 32 + 255) / 256;
    v8u wr[WI];
    #pragma unroll
    for (int i = 0; i < WI; ++i) {
        int t = tid + 256 * i;
        if (t < JT * 32) {
            int row = t >> 5, ch = t & 31;
            wr[i] = *(const v8u*)(Wb + (size_t)(j0 + row) * 256 + ch * 8);
        }
    }
    #pragma unroll
    for (int i = 0; i < 8; ++i) {
        int t = tid + 256 * i;
        int row = t >> 5, ch = t & 31;
        *(v8u*)(Alds + row * 256 + ((ch * 8) ^ ((row & 7) * 8))) = ar[i];
    }
    #pragma unroll
    for (int i = 0; i < WI; ++i) {
        int t = tid + 256 * i;
        if (t < JT * 32) {
            int row = t >> 5, ch = t & 31;
            *(v8u*)(Wlds + row * 256 + ((ch * 8) ^ ((row & 7) * 8))) = wr[i];
        }
    }
    __syncthreads();
    const int lane = tid & 63, wv = tid >> 6;
    const int m = lane & 15, qd = lane >> 4;
    const int arow = wv * 16 + m;
    v4f acc[TPW] = {};
    #pragma unroll
    for (int c = 0; c < 8; ++c) {
        const int koff = c * 32 + qd * 8;
        v8s af = *(const v8s*)(Alds + arow * 256 + (koff ^ ((arow & 7) * 8)));
        #pragma unroll
        for (int t = 0; t < TPW; ++t) {
            int wrow = t * 16 + m;
            v8s wf = *(const v8s*)(Wlds + wrow * 256 + (koff ^ ((wrow & 7) * 8)));
            acc[t] = __builtin_amdgcn_mfma_f32_16x16x32_bf16(af, wf, acc[t], 0, 0, 0);
        }
    }
    #pragma unroll
    for (int t = 0; t < TPW; ++t) {
        int col = j0 + t * 16 + m;
        bool colok = (col < outdim);
        float bv = colok ? bias[col] : 0.f;
        #pragma unroll
        for (int r = 0; r < 4; ++r) {
            int nrow = m0 + wv * 16 + qd * 4 + r;
            if (colok && nrow < N_NODES) {
                float v = acc[t][r] + bv;
                if (RELU) v = fmaxf(v, 0.f);
                size_t idx = (size_t)nrow * outdim + col;
                if (OUTBF) {
                    ((unsigned short*)out)[idx] = f2bf(v);
                    out8[idx] = f2fp8(v);
                } else {
                    ((float*)out)[idx] = v;
                }
            }
        }
    }
}

extern "C" void kernel_launch(void* const* d_in, const int* in_sizes, int n_in,
                              void* d_out, int out_size, void* d_ws, size_t ws_size,
                              hipStream_t stream) {
    const float* x   = (const float*)d_in[0];
    const int*   src = (const int*)d_in[1];
    const int*   dst = (const int*)d_in[2];
    const float* ws1 = (const float*)d_in[3];
    const float* wn1 = (const float*)d_in[4];
    const float* b1  = (const float*)d_in[5];
    const float* ws2 = (const float*)d_in[6];
    const float* wn2 = (const float*)d_in[7];
    const float* b2  = (const float*)d_in[8];
    const float* ws3 = (const float*)d_in[9];
    const float* wn3 = (const float*)d_in[10];
    const float* b3  = (const float*)d_in[11];

    char* p = (char*)d_ws;
    auto alloc = [&](size_t bytes) { char* r = p; p += (bytes + 255) & ~(size_t)255; return r; };
    int*   row_ptr = (int*)alloc((size_t)(N_NODES + 1) * 4);
    int*   srcs    = (int*)alloc((size_t)N_EDGES * 4);
    unsigned int* packed = (unsigned int*)alloc((size_t)N_EDGES * 4);
    int*   parts   = (int*)alloc((size_t)NBIN * NBK * 4);
    int*   gbase   = (int*)alloc((size_t)NBIN * NBK * 4);
    int*   boffB   = (int*)alloc((size_t)NBK * 4);
    int*   btot    = (int*)alloc((size_t)NBK * 4);
    unsigned short* xb    = (unsigned short*)alloc((size_t)N_NODES * DIM * 2);
    unsigned short* meanb = (unsigned short*)alloc((size_t)N_NODES * DIM * 2);
    unsigned short* h1b   = (unsigned short*)alloc((size_t)N_NODES * DIM * 2);
    unsigned short* h2b   = (unsigned short*)alloc((size_t)N_NODES * DIM * 2);
    unsigned char*  h8    = (unsigned char*)alloc((size_t)N_NODES * DIM);
    unsigned short* wb1 = (unsigned short*)alloc((size_t)DIM * 256 * 2);
    unsigned short* wb2 = (unsigned short*)alloc((size_t)DIM * 256 * 2);
    unsigned short* wb3 = (unsigned short*)alloc((size_t)48 * 256 * 2);

    // 1: all conversions + bucket hist partials (no global atomics, no memsets)
    k_prep<<<XCVT_NB + NBIN + WCVT_NB, 256, 0, stream>>>(
        x, xb, (unsigned int*)h8, dst, parts,
        ws1, wn1, ws2, wn2, ws3, wn3, wb1, wb2, wb3);
    // 2-4: CSR
    k_scan2<<<1, 256, 0, stream>>>(parts, gbase, boffB, btot, row_ptr);
    k_bin<<<NBIN, 256, 0, stream>>>(src, dst, gbase, packed);
    k_place<<<NBK, 256, 0, stream>>>(packed, boffB, btot, row_ptr, srcs);

    const int MB = (N_NODES + 63) / 64; // 782
    const int AB = N_NODES / 16;        // 3125

    // layer 1
    k_agg8<<<AB, 256, 0, stream>>>(h8, row_ptr, srcs, meanb);
    k_gemm_lds<64, 4, true, true><<<dim3(MB, 2), 256, 0, stream>>>(xb, meanb, wb1, b1, h1b, h8, DIM);
    // layer 2
    k_agg8<<<AB, 256, 0, stream>>>(h8, row_ptr, srcs, meanb);
    k_gemm_lds<64, 4, true, true><<<dim3(MB, 2), 256, 0, stream>>>(h1b, meanb, wb2, b2, h2b, h8, DIM);
    // layer 3
    k_agg8<<<AB, 256, 0, stream>>>(h8, row_ptr, srcs, meanb);
    k_gemm_lds<48, 3, false, false><<<dim3(MB, 1), 256, 0, stream>>>(h2b, meanb, wb3, b3, d_out, nullptr, OUTD);
}